// Round 12
// baseline (19326.845 us; speedup 1.0000x reference)
//
#include <hip/hip_runtime.h>
#include <hip/hip_bf16.h>
#include <cstdint>

#define S 2048
#define NH 32
#define HD 64
#define NJ 34              // 32 q heads + k + v
#define FUSED_N (NJ * HD)  // 2176
#define HDIM (NH * HD)     // 2048
#define HEAVY_K 128
#define RECENT_W 128
#define START_T 256

typedef __attribute__((ext_vector_type(8))) short short8;
typedef __attribute__((ext_vector_type(4))) float floatx4;

static __device__ __forceinline__ unsigned short f2bf(float f) {
    unsigned u = __float_as_uint(f);
    unsigned r = (u + 0x7FFF + ((u >> 16) & 1)) >> 16; // round-nearest-even
    return (unsigned short)r;
}
static __device__ __forceinline__ float bf2f(unsigned short b) {
    return __uint_as_float(((unsigned)b) << 16);
}

// ---------------------------------------------------------------------------
// MFMA GEMM with on-the-fly bf16x2 split (near-fp32 accuracy):
// C[M][N] = A[M][K] * B[N][K]^T ; A,B f32; C f32.
// ---------------------------------------------------------------------------
#define GBM 128
#define GBN 128
#define GBK 32
__global__ __launch_bounds__(256) void gemm_nt_mfma(const float* __restrict__ A,
                                                    const float* __restrict__ B,
                                                    float* __restrict__ C,
                                                    int M, int N, int K)
{
    __shared__ unsigned short Ash[GBM][GBK + 8], Asl[GBM][GBK + 8];
    __shared__ unsigned short Bsh[GBN][GBK + 8], Bsl[GBN][GBK + 8];
    const int bm = blockIdx.y * GBM;
    const int bn = blockIdx.x * GBN;
    const int tid = threadIdx.x;
    const int w = tid >> 6, lane = tid & 63;
    const int rsub = lane & 15;
    const int d0 = (lane >> 4) * 8;

    floatx4 acc[2][8] = {};

    for (int k0 = 0; k0 < K; k0 += GBK) {
#pragma unroll
        for (int i = 0; i < 4; ++i) {
            int l = tid + i * 256;
            int r = l >> 3;
            int kq = (l & 7) * 4;
            float4 xa = *(const float4*)&A[(size_t)(bm + r) * K + k0 + kq];
            float4 xb = *(const float4*)&B[(size_t)(bn + r) * K + k0 + kq];
            ushort4 ah, al, bh, bl;
            ah.x = f2bf(xa.x); al.x = f2bf(xa.x - bf2f(ah.x));
            ah.y = f2bf(xa.y); al.y = f2bf(xa.y - bf2f(ah.y));
            ah.z = f2bf(xa.z); al.z = f2bf(xa.z - bf2f(ah.z));
            ah.w = f2bf(xa.w); al.w = f2bf(xa.w - bf2f(ah.w));
            bh.x = f2bf(xb.x); bl.x = f2bf(xb.x - bf2f(bh.x));
            bh.y = f2bf(xb.y); bl.y = f2bf(xb.y - bf2f(bh.y));
            bh.z = f2bf(xb.z); bl.z = f2bf(xb.z - bf2f(bh.z));
            bh.w = f2bf(xb.w); bl.w = f2bf(xb.w - bf2f(bh.w));
            *(ushort4*)&Ash[r][kq] = ah;
            *(ushort4*)&Asl[r][kq] = al;
            *(ushort4*)&Bsh[r][kq] = bh;
            *(ushort4*)&Bsl[r][kq] = bl;
        }
        __syncthreads();

        short8 a_h[2], a_l[2];
#pragma unroll
        for (int mt = 0; mt < 2; ++mt) {
            const int row = w * 32 + mt * 16 + rsub;
            a_h[mt] = *(const short8*)&Ash[row][d0];
            a_l[mt] = *(const short8*)&Asl[row][d0];
        }
#pragma unroll
        for (int nt = 0; nt < 8; ++nt) {
            const int col = nt * 16 + rsub;
            short8 b_h = *(const short8*)&Bsh[col][d0];
            short8 b_l = *(const short8*)&Bsl[col][d0];
#pragma unroll
            for (int mt = 0; mt < 2; ++mt) {
                acc[mt][nt] = __builtin_amdgcn_mfma_f32_16x16x32_bf16(a_l[mt], b_h, acc[mt][nt], 0, 0, 0);
                acc[mt][nt] = __builtin_amdgcn_mfma_f32_16x16x32_bf16(a_h[mt], b_l, acc[mt][nt], 0, 0, 0);
                acc[mt][nt] = __builtin_amdgcn_mfma_f32_16x16x32_bf16(a_h[mt], b_h, acc[mt][nt], 0, 0, 0);
            }
        }
        __syncthreads();
    }
#pragma unroll
    for (int mt = 0; mt < 2; ++mt) {
        const int orow = bm + w * 32 + mt * 16 + (lane >> 4) * 4;
#pragma unroll
        for (int nt = 0; nt < 8; ++nt) {
            const int ocol = bn + nt * 16 + rsub;
#pragma unroll
            for (int r = 0; r < 4; ++r)
                C[(size_t)(orow + r) * N + ocol] = acc[mt][nt][r];
        }
    }
}

// ---------------------------------------------------------------------------
// RoPE + split fused -> qb [S][2048] bf16, kb [S][64] bf16, v [S][64] f32
// ---------------------------------------------------------------------------
__global__ __launch_bounds__(256) void rope_split_kernel(const float* __restrict__ fused,
                                                         unsigned short* __restrict__ qb,
                                                         unsigned short* __restrict__ kb,
                                                         float* __restrict__ v)
{
    int idx = blockIdx.x * 256 + threadIdx.x;
    const int total = S * NJ * HD;
    if (idx >= total) return;
    int t = idx / FUSED_N;
    int rem = idx - t * FUSED_N;
    int j = rem >> 6;
    int d = rem & 63;
    float x = fused[idx];
    if (j == 33) { v[t * HD + d] = x; return; }
    int i = d & 31;
    double inv = exp2(-(double)i * (13.287712379549449 / 32.0)); // 10000^(-i/32)
    double ang = (double)t * inv;
    float c  = (float)cos(ang);
    float sn = (float)sin(ang);
    float xo = fused[idx - d + ((d < 32) ? (d + 32) : (d - 32))];
    float rot = (d < 32) ? -xo : xo;
    unsigned short outv = f2bf(x * c + rot * sn);
    if (j == 32) kb[t * HD + d] = outv;
    else         qb[(size_t)t * HDIM + j * HD + d] = outv;
}

// ---------------------------------------------------------------------------
// z_kernel: Zinv[t][h] = 1 / sum_c exp(q_h[t]·k[c]/8)
// ---------------------------------------------------------------------------
__global__ __launch_bounds__(256) void z_kernel(const unsigned short* __restrict__ qb,
                                                const unsigned short* __restrict__ kb,
                                                float* __restrict__ zinv)
{
    const int t0 = blockIdx.x * 32;
    const int h  = blockIdx.y;
    const int w    = threadIdx.x >> 6;
    const int lane = threadIdx.x & 63;
    const int rsub = lane & 15;
    const int d0   = (lane >> 4) * 8;
    __shared__ float zl[4][32];

    short8 a[2][2];
#pragma unroll
    for (int mt = 0; mt < 2; ++mt) {
        const short8* ap = (const short8*)(qb + (size_t)(t0 + mt * 16 + rsub) * HDIM + h * HD + d0);
        a[mt][0] = ap[0];
        a[mt][1] = ap[4];
    }
    float z[2][4] = {};
    for (int nt = 0; nt < 32; ++nt) {
        const int c = w * 512 + nt * 16 + rsub;
        const short8* bp = (const short8*)(kb + (size_t)c * HD + d0);
        short8 b0 = bp[0];
        short8 b1 = bp[4];
#pragma unroll
        for (int mt = 0; mt < 2; ++mt) {
            floatx4 acc = {0.f, 0.f, 0.f, 0.f};
            acc = __builtin_amdgcn_mfma_f32_16x16x32_bf16(a[mt][0], b0, acc, 0, 0, 0);
            acc = __builtin_amdgcn_mfma_f32_16x16x32_bf16(a[mt][1], b1, acc, 0, 0, 0);
#pragma unroll
            for (int r = 0; r < 4; ++r) z[mt][r] += __expf(acc[r] * 0.125f);
        }
    }
#pragma unroll
    for (int mt = 0; mt < 2; ++mt)
#pragma unroll
        for (int r = 0; r < 4; ++r) {
            float zz = z[mt][r];
#pragma unroll
            for (int off = 1; off < 16; off <<= 1) zz += __shfl_xor(zz, off);
            z[mt][r] = zz;
        }
    if (rsub == 0) {
#pragma unroll
        for (int mt = 0; mt < 2; ++mt)
#pragma unroll
            for (int r = 0; r < 4; ++r)
                zl[w][mt * 16 + (lane >> 4) * 4 + r] = z[mt][r];
    }
    __syncthreads();
    if (threadIdx.x < 32) {
        float s = zl[0][threadIdx.x] + zl[1][threadIdx.x] + zl[2][threadIdx.x] + zl[3][threadIdx.x];
        zinv[(size_t)(t0 + threadIdx.x) * NH + h] = 1.0f / s;
    }
}

// ---------------------------------------------------------------------------
// pnorm_kernel: P[t][c] = sum_h exp(q_h[t]·k[c]/8) * zinv[t][h]
// ---------------------------------------------------------------------------
__global__ __launch_bounds__(256) void pnorm_kernel(const unsigned short* __restrict__ qb,
                                                    const unsigned short* __restrict__ kb,
                                                    const float* __restrict__ zinv,
                                                    float* __restrict__ P)
{
    const int t0 = blockIdx.y * 32;
    const int cb = blockIdx.x * 256;
    const int w    = threadIdx.x >> 6;
    const int lane = threadIdx.x & 63;
    const int rsub = lane & 15;
    const int d0   = (lane >> 4) * 8;
    __shared__ float zi[32][33];
    for (int i = threadIdx.x; i < 32 * 32; i += 256) {
        int row = i >> 5, hh = i & 31;
        zi[row][hh] = zinv[(size_t)(t0 + row) * NH + hh];
    }
    __syncthreads();

    float pacc[2][4][4] = {};
    for (int h = 0; h < NH; ++h) {
        short8 a[2][2];
#pragma unroll
        for (int mt = 0; mt < 2; ++mt) {
            const short8* ap = (const short8*)(qb + (size_t)(t0 + mt * 16 + rsub) * HDIM + h * HD + d0);
            a[mt][0] = ap[0];
            a[mt][1] = ap[4];
        }
        float zv[2][4];
#pragma unroll
        for (int mt = 0; mt < 2; ++mt)
#pragma unroll
            for (int r = 0; r < 4; ++r)
                zv[mt][r] = zi[mt * 16 + (lane >> 4) * 4 + r][h];
#pragma unroll
        for (int nt = 0; nt < 4; ++nt) {
            const int c = cb + w * 64 + nt * 16 + rsub;
            const short8* bp = (const short8*)(kb + (size_t)c * HD + d0);
            short8 b0 = bp[0];
            short8 b1 = bp[4];
#pragma unroll
            for (int mt = 0; mt < 2; ++mt) {
                floatx4 acc = {0.f, 0.f, 0.f, 0.f};
                acc = __builtin_amdgcn_mfma_f32_16x16x32_bf16(a[mt][0], b0, acc, 0, 0, 0);
                acc = __builtin_amdgcn_mfma_f32_16x16x32_bf16(a[mt][1], b1, acc, 0, 0, 0);
#pragma unroll
                for (int r = 0; r < 4; ++r)
                    pacc[mt][nt][r] += __expf(acc[r] * 0.125f) * zv[mt][r];
            }
        }
    }
#pragma unroll
    for (int mt = 0; mt < 2; ++mt)
#pragma unroll
        for (int nt = 0; nt < 4; ++nt)
#pragma unroll
            for (int r = 0; r < 4; ++r) {
                int row = t0 + mt * 16 + (lane >> 4) * 4 + r;
                int col = cb + w * 64 + nt * 16 + rsub;
                P[(size_t)row * S + col] = pacc[mt][nt][r];
            }
}

// ---------------------------------------------------------------------------
// acc_init: acc[c] = (c<256 ? sum_{t<256} P[t][c] : 0) + (c<=256 ? P[256][c] : 0)
// ---------------------------------------------------------------------------
__global__ __launch_bounds__(256) void acc_init_kernel(const float* __restrict__ P,
                                                       float* __restrict__ acc_init)
{
    int c = blockIdx.x * 256 + threadIdx.x;
    float s = 0.f;
    if (c < 256) {
        const float* p = P + c;
        float s0 = 0.f, s1 = 0.f, s2 = 0.f, s3 = 0.f;
#pragma unroll 4
        for (int t = 0; t < 256; t += 4) {
            s0 += p[(size_t)t * S];
            s1 += p[(size_t)(t + 1) * S];
            s2 += p[(size_t)(t + 2) * S];
            s3 += p[(size_t)(t + 3) * S];
        }
        s = (s0 + s1) + (s2 + s3);
    }
    if (c <= 256) s += P[(size_t)256 * S + c];
    acc_init[c] = s;
}

// ---------------------------------------------------------------------------
// nv_kernel: NV[c] = candidate value of column c when it becomes newc at step
// t = c+129 (bit-exact vs the sequential accumulation; see round-7 notes).
// Also zeroes the scan-done flag each launch (graph-replay deterministic).
// ---------------------------------------------------------------------------
__global__ __launch_bounds__(256) void nv_kernel(const float* __restrict__ P,
                                                 const float* __restrict__ acc_init,
                                                 float* __restrict__ NV,
                                                 int* __restrict__ done)
{
    if (blockIdx.x == 0 && threadIdx.x == 0) *done = 0;
    int c = 128 + blockIdx.x * 256 + threadIdx.x;
    if (c > 1918) return;
    float s;
    int t0;
    if (c <= 256) { s = acc_init[c]; t0 = 257; }
    else          { s = P[(size_t)c * S + c]; t0 = c + 1; }
    const int t1 = c + 128;
    const float* p = P + c;
    for (int t = t0; t <= t1; ++t)
        s += p[(size_t)t * S];
    NV[c] = s;
}

// ---------------------------------------------------------------------------
// Sequential heavy-hitter scan — single wave at s_setprio(3) + clock-hold
// burners (1024 blocks, ILP-4 FMA, setprio 0). Chain shortened vs r11:
//  * fused single-instruction DPP mins (6 instead of mov+min pairs)
//  * SGPR-base + voffset loads/stores (uniform address streams on SALU)
// Bank discipline identical to r11 (no copies of in-flight load dests).
// Decision logic bit-identical to r11/r9.
// ---------------------------------------------------------------------------
#define GLOAD(dst, ptr) asm volatile("global_load_dword %0, %1, off" : "=v"(dst) : "v"(ptr))
#define GLOAD_S(dst, voff, base) asm volatile("global_load_dword %0, %1, %2" : "=v"(dst) : "v"(voff), "s"(base))
#define GSTORE_S(voff, val, base) asm volatile("global_store_short %0, %1, %2" :: "v"(voff), "v"(val), "s"(base) : "memory")

// one scan step consuming bank (A0x,A1x,AYx,SNx,NVx), then reloading it for t+2
#define SCAN_STEP(t, A0x, A1x, AYx, SNx, NVx)                                        \
    {                                                                                \
        unsigned p0 = (__float_as_uint(v0) & 0xFFFFF800u) | (unsigned)ic0;           \
        unsigned p1 = (__float_as_uint(v1) & 0xFFFFF800u) | (unsigned)ic1;           \
        unsigned xv = p0 < p1 ? p0 : p1;                                             \
        asm("v_min_u32 %0, %0, %0 row_shr:1 row_mask:0xf bank_mask:0xf" : "+v"(xv)); \
        asm("v_min_u32 %0, %0, %0 row_shr:2 row_mask:0xf bank_mask:0xf" : "+v"(xv)); \
        asm("v_min_u32 %0, %0, %0 row_shr:4 row_mask:0xf bank_mask:0xf" : "+v"(xv)); \
        asm("v_min_u32 %0, %0, %0 row_shr:8 row_mask:0xf bank_mask:0xf" : "+v"(xv)); \
        asm("v_min_u32 %0, %0, %0 row_bcast:15 row_mask:0xa bank_mask:0xf" : "+v"(xv));\
        asm("v_min_u32 %0, %0, %0 row_bcast:31 row_mask:0xc bank_mask:0xf" : "+v"(xv));\
        unsigned mpk = (unsigned)__builtin_amdgcn_readlane((int)xv, 63);             \
        asm volatile("s_waitcnt vmcnt(7)" ::: "memory");                             \
        __builtin_amdgcn_sched_barrier(0);                                           \
        const int newc = (t) - 129;                                                  \
        unsigned pn = (__float_as_uint(NVx) & 0xFFFFF800u) | (unsigned)(2047 - newc);\
        const bool evict = mpk < pn;        /* masked strict-<; ties keep heavy */   \
        float pv0 = e0p ? AYx : A0x;                                                 \
        float pv1 = e1p ? AYx : A1x;                                                 \
        const int mcic = (int)(mpk & 2047u);                                         \
        bool e0 = evict && (ic0 == mcic);                                            \
        bool e1 = evict && (ic1 == mcic);                                            \
        v0 = e0 ? (NVx + SNx) : (v0 + pv0);                                          \
        c0 = e0 ? newc : c0;                                                         \
        ic0 = e0 ? (2047 - newc) : ic0;                                              \
        v1 = e1 ? (NVx + SNx) : (v1 + pv1);                                          \
        c1 = e1 ? newc : c1;                                                         \
        ic1 = e1 ? (2047 - newc) : ic1;                                              \
        {                                                                            \
            const unsigned short* hb = heavy + (size_t)(t) * HEAVY_K;                \
            GSTORE_S(vlane0, (unsigned)(unsigned short)c0, hb);                      \
            GSTORE_S(vlane1, (unsigned)(unsigned short)c1, hb);                      \
        }                                                                            \
        e0p = e0; e1p = e1;                                                          \
        {                                                                            \
            const int t2 = ((t) + 2 < S) ? ((t) + 2) : (S - 1);                      \
            const float* P2 = P + (size_t)t2 * S;                                    \
            unsigned vo0 = (unsigned)c0 << 2, vo1 = (unsigned)c1 << 2;               \
            GLOAD_S(A0x, vo0, P2);                                                   \
            GLOAD_S(A1x, vo1, P2);                                                   \
            GLOAD_S(AYx, vzero, P2 + ((t) - 128));     /* P[t+2][newc(t+1)] */       \
            GLOAD_S(SNx, vzero, P2 + (t2 - 129));      /* pnew(t+2)         */       \
            GLOAD_S(NVx, vzero, NV + (t2 - 129));                                    \
        }                                                                            \
    }

__global__ __launch_bounds__(256) void scan_kernel(const float* __restrict__ P,
                                                   const float* __restrict__ acc_init,
                                                   const float* __restrict__ NV,
                                                   unsigned short* __restrict__ heavy,
                                                   int* __restrict__ done)
{
    if (blockIdx.x != 0 || threadIdx.x >= 64) {
        // ---- burner: keep device clocks up until the scan completes ----
        __builtin_amdgcn_s_setprio(0);
        float a = 1.0f + (float)(threadIdx.x & 63);
        float b = 1.000001f;
        float q0 = 0.f, q1 = 1.f, q2 = 2.f, q3 = 3.f;
        while (__hip_atomic_load(done, __ATOMIC_ACQUIRE, __HIP_MEMORY_SCOPE_AGENT) == 0) {
#pragma unroll 8
            for (int i = 0; i < 512; ++i) {
                q0 = fmaf(a, b, q0); q1 = fmaf(a, b, q1);
                q2 = fmaf(a, b, q2); q3 = fmaf(a, b, q3);
            }
            asm volatile("" :: "v"(q0), "v"(q1), "v"(q2), "v"(q3));
        }
        return;
    }

    __builtin_amdgcn_s_setprio(3);          // serial wave wins issue arbitration
    const int lane = threadIdx.x;           // wave 0 of block 0: the serial scan

    heavy[START_T * HEAVY_K + lane] = (unsigned short)lane;
    heavy[START_T * HEAVY_K + 64 + lane] = (unsigned short)(lane + 64);

    int   c0 = lane, c1 = lane + 64;
    int   ic0 = 2047 - c0, ic1 = 2047 - c1;
    float v0 = acc_init[lane], v1 = acc_init[lane + 64];
    const unsigned vlane0 = (unsigned)lane * 2;        // byte offsets into heavy row
    const unsigned vlane1 = (unsigned)lane * 2 + 128;
    unsigned vzero = 0;
    asm volatile("" : "+v"(vzero));                     // pin 0 in a VGPR

    // ---- prologue: bank0 = group(257), bank1 = group(258); drain ----
    float A0a, A1a, AYa, SNa, NVa;   // bank0
    float A0b, A1b, AYb, SNb, NVb;   // bank1
    {
        const float* Pa = P + (size_t)257 * S;
        GLOAD(A0a, Pa + c0);
        GLOAD(A1a, Pa + c1);
        GLOAD(AYa, Pa);               // dummy (e0p false at t=257)
        GLOAD(SNa, Pa + 128);         // pnew(257), newc=128
        GLOAD(NVa, NV + 128);
        const float* Pb = P + (size_t)258 * S;
        GLOAD(A0b, Pb + c0);
        GLOAD(A1b, Pb + c1);
        GLOAD(AYb, Pb + 128);         // P[258][newc(257)]
        GLOAD(SNb, Pb + 129);
        GLOAD(NVb, NV + 129);
    }
    asm volatile("s_waitcnt vmcnt(0)" ::: "memory");
    __builtin_amdgcn_sched_barrier(0);

    bool e0p = false, e1p = false;

    int t = START_T + 1;                       // 257
    for (; t + 1 < S; t += 2) {
        SCAN_STEP(t,     A0a, A1a, AYa, SNa, NVa);
        SCAN_STEP(t + 1, A0b, A1b, AYb, SNb, NVb);
    }
    SCAN_STEP(t, A0a, A1a, AYa, SNa, NVa);     // t = 2047

    if (lane == 0) {
        __threadfence();
        __hip_atomic_store(done, 1, __ATOMIC_RELEASE, __HIP_MEMORY_SCOPE_AGENT);
    }
}

// ---------------------------------------------------------------------------
// Sparse masked attention: row t attends to {128 heavy} ∪ [t-128, t]
// ---------------------------------------------------------------------------
__global__ __launch_bounds__(256) void attn_kernel(const unsigned short* __restrict__ qb,
                                                   const unsigned short* __restrict__ kb,
                                                   const float* __restrict__ v,
                                                   const unsigned short* __restrict__ heavy,
                                                   float* __restrict__ attn)
{
    const int t = blockIdx.x;
    const int tid = threadIdx.x;
    __shared__ float qs[HDIM];
    __shared__ float sc[NH][258];
    __shared__ unsigned short cols[260];
    __shared__ float zpart[NH][8];
    __shared__ float zf[NH];
    const int cnt = (t < START_T) ? (t + 1) : 257;
    {
        const short8* qr = (const short8*)(qb + (size_t)t * HDIM);
        short8 qv = qr[tid];
#pragma unroll
        for (int j = 0; j < 8; ++j) qs[tid * 8 + j] = bf2f((unsigned short)qv[j]);
    }
    if (t < START_T) {
        for (int j = tid; j < cnt; j += 256) cols[j] = (unsigned short)j;
    } else {
        if (tid < 128) cols[tid] = heavy[(size_t)t * HEAVY_K + tid];
        else           cols[tid] = (unsigned short)(t - 256 + tid);
        if (tid == 0)  cols[256] = (unsigned short)t;
    }
    __syncthreads();
    {
        const int h = tid & 31;
        const float* qh = qs + h * HD;
        for (int j = tid >> 5; j < cnt; j += 8) {
            const short8* kc8 = (const short8*)(kb + (size_t)cols[j] * HD);
            float s = 0.f;
#pragma unroll
            for (int dq = 0; dq < 8; ++dq) {
                short8 kv = kc8[dq];
#pragma unroll
                for (int e = 0; e < 8; ++e)
                    s += qh[dq * 8 + e] * bf2f((unsigned short)kv[e]);
            }
            sc[h][j] = s * 0.125f;
        }
    }
    __syncthreads();
    {
        const int h2 = tid >> 3, sub = tid & 7;
        float z = 0.f;
        for (int j = sub; j < cnt; j += 8) {
            float e = __expf(sc[h2][j]);
            sc[h2][j] = e;
            z += e;
        }
        zpart[h2][sub] = z;
    }
    __syncthreads();
    if (tid < NH) {
        float z = 0.f;
#pragma unroll
        for (int s2 = 0; s2 < 8; ++s2) z += zpart[tid][s2];
        zf[tid] = 1.0f / z;
    }
    __syncthreads();
    {
        const int h2 = tid >> 3;
        const int dbase = (tid & 7) * 8;
        float o[8] = {0, 0, 0, 0, 0, 0, 0, 0};
        for (int j = 0; j < cnt; ++j) {
            float p = sc[h2][j];
            const float* vc = v + (size_t)cols[j] * HD + dbase;
            float4 va = *(const float4*)vc;
            float4 vb = *(const float4*)(vc + 4);
            o[0] += p * va.x; o[1] += p * va.y; o[2] += p * va.z; o[3] += p * va.w;
            o[4] += p * vb.x; o[5] += p * vb.y; o[6] += p * vb.z; o[7] += p * vb.w;
        }
        float zi = zf[h2];
        float* op = attn + (size_t)t * HDIM + h2 * HD + dbase;
        float4 ra = make_float4(o[0] * zi, o[1] * zi, o[2] * zi, o[3] * zi);
        float4 rb = make_float4(o[4] * zi, o[5] * zi, o[6] * zi, o[7] * zi);
        *(float4*)op = ra;
        *(float4*)(op + 4) = rb;
    }
}

// ---------------------------------------------------------------------------
extern "C" void kernel_launch(void* const* d_in, const int* in_sizes, int n_in,
                              void* d_out, int out_size, void* d_ws, size_t ws_size,
                              hipStream_t stream)
{
    (void)in_sizes; (void)n_in; (void)out_size; (void)ws_size;
    const float* hs      = (const float*)d_in[0];
    const float* w_qkv   = (const float*)d_in[1];
    const float* w_dense = (const float*)d_in[2];
    float* out = (float*)d_out;
    char* ws = (char*)d_ws;

    // workspace layout (bytes):
    //   [0, 17825792)            fused (2048x2176 f32) -> P (2048x2048 f32) -> attn (2048x2048 f32)
    //   [17825792, 26214400)     qb  bf16 [2048][2048]
    //   [26214400, 26476544)     kb  bf16 [2048][64]
    //   [26476544, 27000832)     v   f32  [2048][64]
    //   [27000832, 27262976)     zinv f32 [2048][32]
    //   [27262976, 27787264)     heavy ushort [2048][128]
    //   [27787264, 27795456)     acc_init f32 [2048]
    //   [27795456, 27803648)     NV f32 [2048]
    //   [27803648, 27803652)     done flag (int)
    float* fused = (float*)(ws);
    float* P     = (float*)(ws);
    float* attn  = (float*)(ws);
    unsigned short* qb = (unsigned short*)(ws + 17825792);
    unsigned short* kb = (unsigned short*)(ws + 26214400);
    float* v           = (float*)(ws + 26476544);
    float* zinv        = (float*)(ws + 27000832);
    unsigned short* heavy = (unsigned short*)(ws + 27262976);
    float* acc_init       = (float*)(ws + 27787264);
    float* NV             = (float*)(ws + 27795456);
    int* done             = (int*)(ws + 27803648);

    dim3 g1(FUSED_N / GBN, S / GBM);     // (17, 16)
    gemm_nt_mfma<<<g1, 256, 0, stream>>>(hs, w_qkv, fused, S, FUSED_N, HDIM);

    int total = S * NJ * HD;
    rope_split_kernel<<<(total + 255) / 256, 256, 0, stream>>>(fused, qb, kb, v);

    dim3 gz(S / 32, NH);
    z_kernel<<<gz, 256, 0, stream>>>(qb, kb, zinv);

    dim3 gp(S / 256, S / 32);
    pnorm_kernel<<<gp, 256, 0, stream>>>(qb, kb, zinv, P);

    acc_init_kernel<<<S / 256, 256, 0, stream>>>(P, acc_init);

    nv_kernel<<<7, 256, 0, stream>>>(P, acc_init, NV, done);

    scan_kernel<<<1024, 256, 0, stream>>>(P, acc_init, NV, heavy, done);

    attn_kernel<<<S, 256, 0, stream>>>(qb, kb, v, heavy, attn);

    dim3 g2(HDIM / GBN, S / GBM);        // (16, 16)
    gemm_nt_mfma<<<g2, 256, 0, stream>>>(attn, w_dense, out, S, HDIM, HDIM);
}

// Round 13
// 1218.003 us; speedup vs baseline: 15.8676x; 15.8676x over previous
//
#include <hip/hip_runtime.h>
#include <hip/hip_bf16.h>
#include <cstdint>

#define S 2048
#define NH 32
#define HD 64
#define NJ 34              // 32 q heads + k + v
#define FUSED_N (NJ * HD)  // 2176
#define HDIM (NH * HD)     // 2048
#define HEAVY_K 128
#define RECENT_W 128
#define START_T 256

typedef __attribute__((ext_vector_type(8))) short short8;
typedef __attribute__((ext_vector_type(4))) float floatx4;

static __device__ __forceinline__ unsigned short f2bf(float f) {
    unsigned u = __float_as_uint(f);
    unsigned r = (u + 0x7FFF + ((u >> 16) & 1)) >> 16; // round-nearest-even
    return (unsigned short)r;
}
static __device__ __forceinline__ float bf2f(unsigned short b) {
    return __uint_as_float(((unsigned)b) << 16);
}

// ---------------------------------------------------------------------------
// MFMA GEMM with on-the-fly bf16x2 split (near-fp32 accuracy):
// C[M][N] = A[M][K] * B[N][K]^T ; A,B f32; C f32.
// ---------------------------------------------------------------------------
#define GBM 128
#define GBN 128
#define GBK 32
__global__ __launch_bounds__(256) void gemm_nt_mfma(const float* __restrict__ A,
                                                    const float* __restrict__ B,
                                                    float* __restrict__ C,
                                                    int M, int N, int K)
{
    __shared__ unsigned short Ash[GBM][GBK + 8], Asl[GBM][GBK + 8];
    __shared__ unsigned short Bsh[GBN][GBK + 8], Bsl[GBN][GBK + 8];
    const int bm = blockIdx.y * GBM;
    const int bn = blockIdx.x * GBN;
    const int tid = threadIdx.x;
    const int w = tid >> 6, lane = tid & 63;
    const int rsub = lane & 15;
    const int d0 = (lane >> 4) * 8;

    floatx4 acc[2][8] = {};

    for (int k0 = 0; k0 < K; k0 += GBK) {
#pragma unroll
        for (int i = 0; i < 4; ++i) {
            int l = tid + i * 256;
            int r = l >> 3;
            int kq = (l & 7) * 4;
            float4 xa = *(const float4*)&A[(size_t)(bm + r) * K + k0 + kq];
            float4 xb = *(const float4*)&B[(size_t)(bn + r) * K + k0 + kq];
            ushort4 ah, al, bh, bl;
            ah.x = f2bf(xa.x); al.x = f2bf(xa.x - bf2f(ah.x));
            ah.y = f2bf(xa.y); al.y = f2bf(xa.y - bf2f(ah.y));
            ah.z = f2bf(xa.z); al.z = f2bf(xa.z - bf2f(ah.z));
            ah.w = f2bf(xa.w); al.w = f2bf(xa.w - bf2f(ah.w));
            bh.x = f2bf(xb.x); bl.x = f2bf(xb.x - bf2f(bh.x));
            bh.y = f2bf(xb.y); bl.y = f2bf(xb.y - bf2f(bh.y));
            bh.z = f2bf(xb.z); bl.z = f2bf(xb.z - bf2f(bh.z));
            bh.w = f2bf(xb.w); bl.w = f2bf(xb.w - bf2f(bh.w));
            *(ushort4*)&Ash[r][kq] = ah;
            *(ushort4*)&Asl[r][kq] = al;
            *(ushort4*)&Bsh[r][kq] = bh;
            *(ushort4*)&Bsl[r][kq] = bl;
        }
        __syncthreads();

        short8 a_h[2], a_l[2];
#pragma unroll
        for (int mt = 0; mt < 2; ++mt) {
            const int row = w * 32 + mt * 16 + rsub;
            a_h[mt] = *(const short8*)&Ash[row][d0];
            a_l[mt] = *(const short8*)&Asl[row][d0];
        }
#pragma unroll
        for (int nt = 0; nt < 8; ++nt) {
            const int col = nt * 16 + rsub;
            short8 b_h = *(const short8*)&Bsh[col][d0];
            short8 b_l = *(const short8*)&Bsl[col][d0];
#pragma unroll
            for (int mt = 0; mt < 2; ++mt) {
                acc[mt][nt] = __builtin_amdgcn_mfma_f32_16x16x32_bf16(a_l[mt], b_h, acc[mt][nt], 0, 0, 0);
                acc[mt][nt] = __builtin_amdgcn_mfma_f32_16x16x32_bf16(a_h[mt], b_l, acc[mt][nt], 0, 0, 0);
                acc[mt][nt] = __builtin_amdgcn_mfma_f32_16x16x32_bf16(a_h[mt], b_h, acc[mt][nt], 0, 0, 0);
            }
        }
        __syncthreads();
    }
#pragma unroll
    for (int mt = 0; mt < 2; ++mt) {
        const int orow = bm + w * 32 + mt * 16 + (lane >> 4) * 4;
#pragma unroll
        for (int nt = 0; nt < 8; ++nt) {
            const int ocol = bn + nt * 16 + rsub;
#pragma unroll
            for (int r = 0; r < 4; ++r)
                C[(size_t)(orow + r) * N + ocol] = acc[mt][nt][r];
        }
    }
}

// ---------------------------------------------------------------------------
// RoPE + split fused -> qb [S][2048] bf16, kb [S][64] bf16, v [S][64] f32
// ---------------------------------------------------------------------------
__global__ __launch_bounds__(256) void rope_split_kernel(const float* __restrict__ fused,
                                                         unsigned short* __restrict__ qb,
                                                         unsigned short* __restrict__ kb,
                                                         float* __restrict__ v)
{
    int idx = blockIdx.x * 256 + threadIdx.x;
    const int total = S * NJ * HD;
    if (idx >= total) return;
    int t = idx / FUSED_N;
    int rem = idx - t * FUSED_N;
    int j = rem >> 6;
    int d = rem & 63;
    float x = fused[idx];
    if (j == 33) { v[t * HD + d] = x; return; }
    int i = d & 31;
    double inv = exp2(-(double)i * (13.287712379549449 / 32.0)); // 10000^(-i/32)
    double ang = (double)t * inv;
    float c  = (float)cos(ang);
    float sn = (float)sin(ang);
    float xo = fused[idx - d + ((d < 32) ? (d + 32) : (d - 32))];
    float rot = (d < 32) ? -xo : xo;
    unsigned short outv = f2bf(x * c + rot * sn);
    if (j == 32) kb[t * HD + d] = outv;
    else         qb[(size_t)t * HDIM + j * HD + d] = outv;
}

// ---------------------------------------------------------------------------
// z_kernel: Zinv[t][h] = 1 / sum_c exp(q_h[t]·k[c]/8)
// ---------------------------------------------------------------------------
__global__ __launch_bounds__(256) void z_kernel(const unsigned short* __restrict__ qb,
                                                const unsigned short* __restrict__ kb,
                                                float* __restrict__ zinv)
{
    const int t0 = blockIdx.x * 32;
    const int h  = blockIdx.y;
    const int w    = threadIdx.x >> 6;
    const int lane = threadIdx.x & 63;
    const int rsub = lane & 15;
    const int d0   = (lane >> 4) * 8;
    __shared__ float zl[4][32];

    short8 a[2][2];
#pragma unroll
    for (int mt = 0; mt < 2; ++mt) {
        const short8* ap = (const short8*)(qb + (size_t)(t0 + mt * 16 + rsub) * HDIM + h * HD + d0);
        a[mt][0] = ap[0];
        a[mt][1] = ap[4];
    }
    float z[2][4] = {};
    for (int nt = 0; nt < 32; ++nt) {
        const int c = w * 512 + nt * 16 + rsub;
        const short8* bp = (const short8*)(kb + (size_t)c * HD + d0);
        short8 b0 = bp[0];
        short8 b1 = bp[4];
#pragma unroll
        for (int mt = 0; mt < 2; ++mt) {
            floatx4 acc = {0.f, 0.f, 0.f, 0.f};
            acc = __builtin_amdgcn_mfma_f32_16x16x32_bf16(a[mt][0], b0, acc, 0, 0, 0);
            acc = __builtin_amdgcn_mfma_f32_16x16x32_bf16(a[mt][1], b1, acc, 0, 0, 0);
#pragma unroll
            for (int r = 0; r < 4; ++r) z[mt][r] += __expf(acc[r] * 0.125f);
        }
    }
#pragma unroll
    for (int mt = 0; mt < 2; ++mt)
#pragma unroll
        for (int r = 0; r < 4; ++r) {
            float zz = z[mt][r];
#pragma unroll
            for (int off = 1; off < 16; off <<= 1) zz += __shfl_xor(zz, off);
            z[mt][r] = zz;
        }
    if (rsub == 0) {
#pragma unroll
        for (int mt = 0; mt < 2; ++mt)
#pragma unroll
            for (int r = 0; r < 4; ++r)
                zl[w][mt * 16 + (lane >> 4) * 4 + r] = z[mt][r];
    }
    __syncthreads();
    if (threadIdx.x < 32) {
        float s = zl[0][threadIdx.x] + zl[1][threadIdx.x] + zl[2][threadIdx.x] + zl[3][threadIdx.x];
        zinv[(size_t)(t0 + threadIdx.x) * NH + h] = 1.0f / s;
    }
}

// ---------------------------------------------------------------------------
// pnorm_kernel: P[t][c] = sum_h exp(q_h[t]·k[c]/8) * zinv[t][h]
// ---------------------------------------------------------------------------
__global__ __launch_bounds__(256) void pnorm_kernel(const unsigned short* __restrict__ qb,
                                                    const unsigned short* __restrict__ kb,
                                                    const float* __restrict__ zinv,
                                                    float* __restrict__ P)
{
    const int t0 = blockIdx.y * 32;
    const int cb = blockIdx.x * 256;
    const int w    = threadIdx.x >> 6;
    const int lane = threadIdx.x & 63;
    const int rsub = lane & 15;
    const int d0   = (lane >> 4) * 8;
    __shared__ float zi[32][33];
    for (int i = threadIdx.x; i < 32 * 32; i += 256) {
        int row = i >> 5, hh = i & 31;
        zi[row][hh] = zinv[(size_t)(t0 + row) * NH + hh];
    }
    __syncthreads();

    float pacc[2][4][4] = {};
    for (int h = 0; h < NH; ++h) {
        short8 a[2][2];
#pragma unroll
        for (int mt = 0; mt < 2; ++mt) {
            const short8* ap = (const short8*)(qb + (size_t)(t0 + mt * 16 + rsub) * HDIM + h * HD + d0);
            a[mt][0] = ap[0];
            a[mt][1] = ap[4];
        }
        float zv[2][4];
#pragma unroll
        for (int mt = 0; mt < 2; ++mt)
#pragma unroll
            for (int r = 0; r < 4; ++r)
                zv[mt][r] = zi[mt * 16 + (lane >> 4) * 4 + r][h];
#pragma unroll
        for (int nt = 0; nt < 4; ++nt) {
            const int c = cb + w * 64 + nt * 16 + rsub;
            const short8* bp = (const short8*)(kb + (size_t)c * HD + d0);
            short8 b0 = bp[0];
            short8 b1 = bp[4];
#pragma unroll
            for (int mt = 0; mt < 2; ++mt) {
                floatx4 acc = {0.f, 0.f, 0.f, 0.f};
                acc = __builtin_amdgcn_mfma_f32_16x16x32_bf16(a[mt][0], b0, acc, 0, 0, 0);
                acc = __builtin_amdgcn_mfma_f32_16x16x32_bf16(a[mt][1], b1, acc, 0, 0, 0);
#pragma unroll
                for (int r = 0; r < 4; ++r)
                    pacc[mt][nt][r] += __expf(acc[r] * 0.125f) * zv[mt][r];
            }
        }
    }
#pragma unroll
    for (int mt = 0; mt < 2; ++mt)
#pragma unroll
        for (int nt = 0; nt < 4; ++nt)
#pragma unroll
            for (int r = 0; r < 4; ++r) {
                int row = t0 + mt * 16 + (lane >> 4) * 4 + r;
                int col = cb + w * 64 + nt * 16 + rsub;
                P[(size_t)row * S + col] = pacc[mt][nt][r];
            }
}

// ---------------------------------------------------------------------------
// acc_init: acc[c] = (c<256 ? sum_{t<256} P[t][c] : 0) + (c<=256 ? P[256][c] : 0)
// ---------------------------------------------------------------------------
__global__ __launch_bounds__(256) void acc_init_kernel(const float* __restrict__ P,
                                                       float* __restrict__ acc_init)
{
    int c = blockIdx.x * 256 + threadIdx.x;
    float s = 0.f;
    if (c < 256) {
        const float* p = P + c;
        float s0 = 0.f, s1 = 0.f, s2 = 0.f, s3 = 0.f;
#pragma unroll 4
        for (int t = 0; t < 256; t += 4) {
            s0 += p[(size_t)t * S];
            s1 += p[(size_t)(t + 1) * S];
            s2 += p[(size_t)(t + 2) * S];
            s3 += p[(size_t)(t + 3) * S];
        }
        s = (s0 + s1) + (s2 + s3);
    }
    if (c <= 256) s += P[(size_t)256 * S + c];
    acc_init[c] = s;
}

// ---------------------------------------------------------------------------
// nv_kernel: NV[c] = candidate value of column c when it becomes newc at step
// t = c+129 (bit-exact vs the sequential accumulation; see round-7 notes).
// Also zeroes the scan-done flag each launch (graph-replay deterministic).
// ---------------------------------------------------------------------------
__global__ __launch_bounds__(256) void nv_kernel(const float* __restrict__ P,
                                                 const float* __restrict__ acc_init,
                                                 float* __restrict__ NV,
                                                 int* __restrict__ done)
{
    if (blockIdx.x == 0 && threadIdx.x == 0) *done = 0;
    int c = 128 + blockIdx.x * 256 + threadIdx.x;
    if (c > 1918) return;
    float s;
    int t0;
    if (c <= 256) { s = acc_init[c]; t0 = 257; }
    else          { s = P[(size_t)c * S + c]; t0 = c + 1; }
    const int t1 = c + 128;
    const float* p = P + c;
    for (int t = t0; t <= t1; ++t)
        s += p[(size_t)t * S];
    NV[c] = s;
}

// ---------------------------------------------------------------------------
// Sequential heavy-hitter scan — r11 burner config (256 blocks, serial-FMA
// burner that stalls 3/4 cycles, NO setprio) + r12's verified chain opts
// (fused DPP v_min, SGPR-base addressing). r12's regression isolated to the
// burner change (1024 blocks, ILP-4, setprio): correct output, 29x slower.
// Bank discipline (no copies of in-flight load dests) identical to r11.
// ---------------------------------------------------------------------------
#define GLOAD(dst, ptr) asm volatile("global_load_dword %0, %1, off" : "=v"(dst) : "v"(ptr))
#define GLOAD_S(dst, voff, base) asm volatile("global_load_dword %0, %1, %2" : "=v"(dst) : "v"(voff), "s"(base))
#define GSTORE_S(voff, val, base) asm volatile("global_store_short %0, %1, %2" :: "v"(voff), "v"(val), "s"(base) : "memory")

// one scan step consuming bank (A0x,A1x,AYx,SNx,NVx), then reloading it for t+2
#define SCAN_STEP(t, A0x, A1x, AYx, SNx, NVx)                                        \
    {                                                                                \
        unsigned p0 = (__float_as_uint(v0) & 0xFFFFF800u) | (unsigned)ic0;           \
        unsigned p1 = (__float_as_uint(v1) & 0xFFFFF800u) | (unsigned)ic1;           \
        unsigned xv = p0 < p1 ? p0 : p1;                                             \
        asm("v_min_u32 %0, %0, %0 row_shr:1 row_mask:0xf bank_mask:0xf" : "+v"(xv)); \
        asm("v_min_u32 %0, %0, %0 row_shr:2 row_mask:0xf bank_mask:0xf" : "+v"(xv)); \
        asm("v_min_u32 %0, %0, %0 row_shr:4 row_mask:0xf bank_mask:0xf" : "+v"(xv)); \
        asm("v_min_u32 %0, %0, %0 row_shr:8 row_mask:0xf bank_mask:0xf" : "+v"(xv)); \
        asm("v_min_u32 %0, %0, %0 row_bcast:15 row_mask:0xa bank_mask:0xf" : "+v"(xv));\
        asm("v_min_u32 %0, %0, %0 row_bcast:31 row_mask:0xc bank_mask:0xf" : "+v"(xv));\
        unsigned mpk = (unsigned)__builtin_amdgcn_readlane((int)xv, 63);             \
        asm volatile("s_waitcnt vmcnt(7)" ::: "memory");                             \
        __builtin_amdgcn_sched_barrier(0);                                           \
        const int newc = (t) - 129;                                                  \
        unsigned pn = (__float_as_uint(NVx) & 0xFFFFF800u) | (unsigned)(2047 - newc);\
        const bool evict = mpk < pn;        /* masked strict-<; ties keep heavy */   \
        float pv0 = e0p ? AYx : A0x;                                                 \
        float pv1 = e1p ? AYx : A1x;                                                 \
        const int mcic = (int)(mpk & 2047u);                                         \
        bool e0 = evict && (ic0 == mcic);                                            \
        bool e1 = evict && (ic1 == mcic);                                            \
        v0 = e0 ? (NVx + SNx) : (v0 + pv0);                                          \
        c0 = e0 ? newc : c0;                                                         \
        ic0 = e0 ? (2047 - newc) : ic0;                                              \
        v1 = e1 ? (NVx + SNx) : (v1 + pv1);                                          \
        c1 = e1 ? newc : c1;                                                         \
        ic1 = e1 ? (2047 - newc) : ic1;                                              \
        {                                                                            \
            const unsigned short* hb = heavy + (size_t)(t) * HEAVY_K;                \
            GSTORE_S(vlane0, (unsigned)(unsigned short)c0, hb);                      \
            GSTORE_S(vlane1, (unsigned)(unsigned short)c1, hb);                      \
        }                                                                            \
        e0p = e0; e1p = e1;                                                          \
        {                                                                            \
            const int t2 = ((t) + 2 < S) ? ((t) + 2) : (S - 1);                      \
            const float* P2 = P + (size_t)t2 * S;                                    \
            unsigned vo0 = (unsigned)c0 << 2, vo1 = (unsigned)c1 << 2;               \
            GLOAD_S(A0x, vo0, P2);                                                   \
            GLOAD_S(A1x, vo1, P2);                                                   \
            GLOAD_S(AYx, vzero, P2 + ((t) - 128));     /* P[t+2][newc(t+1)] */       \
            GLOAD_S(SNx, vzero, P2 + (t2 - 129));      /* pnew(t+2)         */       \
            GLOAD_S(NVx, vzero, NV + (t2 - 129));                                    \
        }                                                                            \
    }

__global__ __launch_bounds__(256) void scan_kernel(const float* __restrict__ P,
                                                   const float* __restrict__ acc_init,
                                                   const float* __restrict__ NV,
                                                   unsigned short* __restrict__ heavy,
                                                   int* __restrict__ done)
{
    if (blockIdx.x != 0 || threadIdx.x >= 64) {
        // ---- burner (r11 exact): serial-dependent FMA chain, gentle poll ----
        float a = 1.0f + (float)(threadIdx.x + blockIdx.x * 256);
        float b = 1.000001f, c = 0.f;
        while (__hip_atomic_load(done, __ATOMIC_ACQUIRE, __HIP_MEMORY_SCOPE_AGENT) == 0) {
#pragma unroll 16
            for (int i = 0; i < 1024; ++i) c = fmaf(a, b, c);
            asm volatile("" :: "v"(c));
        }
        return;
    }

    const int lane = threadIdx.x;           // wave 0 of block 0: the serial scan

    heavy[START_T * HEAVY_K + lane] = (unsigned short)lane;
    heavy[START_T * HEAVY_K + 64 + lane] = (unsigned short)(lane + 64);

    int   c0 = lane, c1 = lane + 64;
    int   ic0 = 2047 - c0, ic1 = 2047 - c1;
    float v0 = acc_init[lane], v1 = acc_init[lane + 64];
    const unsigned vlane0 = (unsigned)lane * 2;        // byte offsets into heavy row
    const unsigned vlane1 = (unsigned)lane * 2 + 128;
    unsigned vzero = 0;
    asm volatile("" : "+v"(vzero));                     // pin 0 in a VGPR

    // ---- prologue: bank0 = group(257), bank1 = group(258); drain ----
    float A0a, A1a, AYa, SNa, NVa;   // bank0
    float A0b, A1b, AYb, SNb, NVb;   // bank1
    {
        const float* Pa = P + (size_t)257 * S;
        GLOAD(A0a, Pa + c0);
        GLOAD(A1a, Pa + c1);
        GLOAD(AYa, Pa);               // dummy (e0p false at t=257)
        GLOAD(SNa, Pa + 128);         // pnew(257), newc=128
        GLOAD(NVa, NV + 128);
        const float* Pb = P + (size_t)258 * S;
        GLOAD(A0b, Pb + c0);
        GLOAD(A1b, Pb + c1);
        GLOAD(AYb, Pb + 128);         // P[258][newc(257)]
        GLOAD(SNb, Pb + 129);
        GLOAD(NVb, NV + 129);
    }
    asm volatile("s_waitcnt vmcnt(0)" ::: "memory");
    __builtin_amdgcn_sched_barrier(0);

    bool e0p = false, e1p = false;

    int t = START_T + 1;                       // 257
    for (; t + 1 < S; t += 2) {
        SCAN_STEP(t,     A0a, A1a, AYa, SNa, NVa);
        SCAN_STEP(t + 1, A0b, A1b, AYb, SNb, NVb);
    }
    SCAN_STEP(t, A0a, A1a, AYa, SNa, NVa);     // t = 2047

    if (lane == 0) {
        __threadfence();
        __hip_atomic_store(done, 1, __ATOMIC_RELEASE, __HIP_MEMORY_SCOPE_AGENT);
    }
}

// ---------------------------------------------------------------------------
// Sparse masked attention: row t attends to {128 heavy} ∪ [t-128, t]
// ---------------------------------------------------------------------------
__global__ __launch_bounds__(256) void attn_kernel(const unsigned short* __restrict__ qb,
                                                   const unsigned short* __restrict__ kb,
                                                   const float* __restrict__ v,
                                                   const unsigned short* __restrict__ heavy,
                                                   float* __restrict__ attn)
{
    const int t = blockIdx.x;
    const int tid = threadIdx.x;
    __shared__ float qs[HDIM];
    __shared__ float sc[NH][258];
    __shared__ unsigned short cols[260];
    __shared__ float zpart[NH][8];
    __shared__ float zf[NH];
    const int cnt = (t < START_T) ? (t + 1) : 257;
    {
        const short8* qr = (const short8*)(qb + (size_t)t * HDIM);
        short8 qv = qr[tid];
#pragma unroll
        for (int j = 0; j < 8; ++j) qs[tid * 8 + j] = bf2f((unsigned short)qv[j]);
    }
    if (t < START_T) {
        for (int j = tid; j < cnt; j += 256) cols[j] = (unsigned short)j;
    } else {
        if (tid < 128) cols[tid] = heavy[(size_t)t * HEAVY_K + tid];
        else           cols[tid] = (unsigned short)(t - 256 + tid);
        if (tid == 0)  cols[256] = (unsigned short)t;
    }
    __syncthreads();
    {
        const int h = tid & 31;
        const float* qh = qs + h * HD;
        for (int j = tid >> 5; j < cnt; j += 8) {
            const short8* kc8 = (const short8*)(kb + (size_t)cols[j] * HD);
            float s = 0.f;
#pragma unroll
            for (int dq = 0; dq < 8; ++dq) {
                short8 kv = kc8[dq];
#pragma unroll
                for (int e = 0; e < 8; ++e)
                    s += qh[dq * 8 + e] * bf2f((unsigned short)kv[e]);
            }
            sc[h][j] = s * 0.125f;
        }
    }
    __syncthreads();
    {
        const int h2 = tid >> 3, sub = tid & 7;
        float z = 0.f;
        for (int j = sub; j < cnt; j += 8) {
            float e = __expf(sc[h2][j]);
            sc[h2][j] = e;
            z += e;
        }
        zpart[h2][sub] = z;
    }
    __syncthreads();
    if (tid < NH) {
        float z = 0.f;
#pragma unroll
        for (int s2 = 0; s2 < 8; ++s2) z += zpart[tid][s2];
        zf[tid] = 1.0f / z;
    }
    __syncthreads();
    {
        const int h2 = tid >> 3;
        const int dbase = (tid & 7) * 8;
        float o[8] = {0, 0, 0, 0, 0, 0, 0, 0};
        for (int j = 0; j < cnt; ++j) {
            float p = sc[h2][j];
            const float* vc = v + (size_t)cols[j] * HD + dbase;
            float4 va = *(const float4*)vc;
            float4 vb = *(const float4*)(vc + 4);
            o[0] += p * va.x; o[1] += p * va.y; o[2] += p * va.z; o[3] += p * va.w;
            o[4] += p * vb.x; o[5] += p * vb.y; o[6] += p * vb.z; o[7] += p * vb.w;
        }
        float zi = zf[h2];
        float* op = attn + (size_t)t * HDIM + h2 * HD + dbase;
        float4 ra = make_float4(o[0] * zi, o[1] * zi, o[2] * zi, o[3] * zi);
        float4 rb = make_float4(o[4] * zi, o[5] * zi, o[6] * zi, o[7] * zi);
        *(float4*)op = ra;
        *(float4*)(op + 4) = rb;
    }
}

// ---------------------------------------------------------------------------
extern "C" void kernel_launch(void* const* d_in, const int* in_sizes, int n_in,
                              void* d_out, int out_size, void* d_ws, size_t ws_size,
                              hipStream_t stream)
{
    (void)in_sizes; (void)n_in; (void)out_size; (void)ws_size;
    const float* hs      = (const float*)d_in[0];
    const float* w_qkv   = (const float*)d_in[1];
    const float* w_dense = (const float*)d_in[2];
    float* out = (float*)d_out;
    char* ws = (char*)d_ws;

    // workspace layout (bytes):
    //   [0, 17825792)            fused (2048x2176 f32) -> P (2048x2048 f32) -> attn (2048x2048 f32)
    //   [17825792, 26214400)     qb  bf16 [2048][2048]
    //   [26214400, 26476544)     kb  bf16 [2048][64]
    //   [26476544, 27000832)     v   f32  [2048][64]
    //   [27000832, 27262976)     zinv f32 [2048][32]
    //   [27262976, 27787264)     heavy ushort [2048][128]
    //   [27787264, 27795456)     acc_init f32 [2048]
    //   [27795456, 27803648)     NV f32 [2048]
    //   [27803648, 27803652)     done flag (int)
    float* fused = (float*)(ws);
    float* P     = (float*)(ws);
    float* attn  = (float*)(ws);
    unsigned short* qb = (unsigned short*)(ws + 17825792);
    unsigned short* kb = (unsigned short*)(ws + 26214400);
    float* v           = (float*)(ws + 26476544);
    float* zinv        = (float*)(ws + 27000832);
    unsigned short* heavy = (unsigned short*)(ws + 27262976);
    float* acc_init       = (float*)(ws + 27787264);
    float* NV             = (float*)(ws + 27795456);
    int* done             = (int*)(ws + 27803648);

    dim3 g1(FUSED_N / GBN, S / GBM);     // (17, 16)
    gemm_nt_mfma<<<g1, 256, 0, stream>>>(hs, w_qkv, fused, S, FUSED_N, HDIM);

    int total = S * NJ * HD;
    rope_split_kernel<<<(total + 255) / 256, 256, 0, stream>>>(fused, qb, kb, v);

    dim3 gz(S / 32, NH);
    z_kernel<<<gz, 256, 0, stream>>>(qb, kb, zinv);

    dim3 gp(S / 256, S / 32);
    pnorm_kernel<<<gp, 256, 0, stream>>>(qb, kb, zinv, P);

    acc_init_kernel<<<S / 256, 256, 0, stream>>>(P, acc_init);

    nv_kernel<<<7, 256, 0, stream>>>(P, acc_init, NV, done);

    scan_kernel<<<256, 256, 0, stream>>>(P, acc_init, NV, heavy, done);

    attn_kernel<<<S, 256, 0, stream>>>(qb, kb, v, heavy, attn);

    dim3 g2(HDIM / GBN, S / GBM);        // (16, 16)
    gemm_nt_mfma<<<g2, 256, 0, stream>>>(attn, w_dense, out, S, HDIM, HDIM);
}

// Round 14
// 1151.816 us; speedup vs baseline: 16.7795x; 1.0575x over previous
//
#include <hip/hip_runtime.h>
#include <hip/hip_bf16.h>
#include <cstdint>

#define S 2048
#define NH 32
#define HD 64
#define NJ 34              // 32 q heads + k + v
#define FUSED_N (NJ * HD)  // 2176
#define HDIM (NH * HD)     // 2048
#define HEAVY_K 128
#define RECENT_W 128
#define START_T 256

typedef __attribute__((ext_vector_type(8))) short short8;
typedef __attribute__((ext_vector_type(4))) float floatx4;

static __device__ __forceinline__ unsigned short f2bf(float f) {
    unsigned u = __float_as_uint(f);
    unsigned r = (u + 0x7FFF + ((u >> 16) & 1)) >> 16; // round-nearest-even
    return (unsigned short)r;
}
static __device__ __forceinline__ float bf2f(unsigned short b) {
    return __uint_as_float(((unsigned)b) << 16);
}

// ---------------------------------------------------------------------------
// MFMA GEMM with on-the-fly bf16x2 split (near-fp32 accuracy):
// C[M][N] = A[M][K] * B[N][K]^T ; A,B f32; C f32.
// ---------------------------------------------------------------------------
#define GBM 128
#define GBN 128
#define GBK 32
__global__ __launch_bounds__(256) void gemm_nt_mfma(const float* __restrict__ A,
                                                    const float* __restrict__ B,
                                                    float* __restrict__ C,
                                                    int M, int N, int K)
{
    __shared__ unsigned short Ash[GBM][GBK + 8], Asl[GBM][GBK + 8];
    __shared__ unsigned short Bsh[GBN][GBK + 8], Bsl[GBN][GBK + 8];
    const int bm = blockIdx.y * GBM;
    const int bn = blockIdx.x * GBN;
    const int tid = threadIdx.x;
    const int w = tid >> 6, lane = tid & 63;
    const int rsub = lane & 15;
    const int d0 = (lane >> 4) * 8;

    floatx4 acc[2][8] = {};

    for (int k0 = 0; k0 < K; k0 += GBK) {
#pragma unroll
        for (int i = 0; i < 4; ++i) {
            int l = tid + i * 256;
            int r = l >> 3;
            int kq = (l & 7) * 4;
            float4 xa = *(const float4*)&A[(size_t)(bm + r) * K + k0 + kq];
            float4 xb = *(const float4*)&B[(size_t)(bn + r) * K + k0 + kq];
            ushort4 ah, al, bh, bl;
            ah.x = f2bf(xa.x); al.x = f2bf(xa.x - bf2f(ah.x));
            ah.y = f2bf(xa.y); al.y = f2bf(xa.y - bf2f(ah.y));
            ah.z = f2bf(xa.z); al.z = f2bf(xa.z - bf2f(ah.z));
            ah.w = f2bf(xa.w); al.w = f2bf(xa.w - bf2f(ah.w));
            bh.x = f2bf(xb.x); bl.x = f2bf(xb.x - bf2f(bh.x));
            bh.y = f2bf(xb.y); bl.y = f2bf(xb.y - bf2f(bh.y));
            bh.z = f2bf(xb.z); bl.z = f2bf(xb.z - bf2f(bh.z));
            bh.w = f2bf(xb.w); bl.w = f2bf(xb.w - bf2f(bh.w));
            *(ushort4*)&Ash[r][kq] = ah;
            *(ushort4*)&Asl[r][kq] = al;
            *(ushort4*)&Bsh[r][kq] = bh;
            *(ushort4*)&Bsl[r][kq] = bl;
        }
        __syncthreads();

        short8 a_h[2], a_l[2];
#pragma unroll
        for (int mt = 0; mt < 2; ++mt) {
            const int row = w * 32 + mt * 16 + rsub;
            a_h[mt] = *(const short8*)&Ash[row][d0];
            a_l[mt] = *(const short8*)&Asl[row][d0];
        }
#pragma unroll
        for (int nt = 0; nt < 8; ++nt) {
            const int col = nt * 16 + rsub;
            short8 b_h = *(const short8*)&Bsh[col][d0];
            short8 b_l = *(const short8*)&Bsl[col][d0];
#pragma unroll
            for (int mt = 0; mt < 2; ++mt) {
                acc[mt][nt] = __builtin_amdgcn_mfma_f32_16x16x32_bf16(a_l[mt], b_h, acc[mt][nt], 0, 0, 0);
                acc[mt][nt] = __builtin_amdgcn_mfma_f32_16x16x32_bf16(a_h[mt], b_l, acc[mt][nt], 0, 0, 0);
                acc[mt][nt] = __builtin_amdgcn_mfma_f32_16x16x32_bf16(a_h[mt], b_h, acc[mt][nt], 0, 0, 0);
            }
        }
        __syncthreads();
    }
#pragma unroll
    for (int mt = 0; mt < 2; ++mt) {
        const int orow = bm + w * 32 + mt * 16 + (lane >> 4) * 4;
#pragma unroll
        for (int nt = 0; nt < 8; ++nt) {
            const int ocol = bn + nt * 16 + rsub;
#pragma unroll
            for (int r = 0; r < 4; ++r)
                C[(size_t)(orow + r) * N + ocol] = acc[mt][nt][r];
        }
    }
}

// ---------------------------------------------------------------------------
// RoPE + split fused -> qb [S][2048] bf16, kb [S][64] bf16, v [S][64] f32
// ---------------------------------------------------------------------------
__global__ __launch_bounds__(256) void rope_split_kernel(const float* __restrict__ fused,
                                                         unsigned short* __restrict__ qb,
                                                         unsigned short* __restrict__ kb,
                                                         float* __restrict__ v)
{
    int idx = blockIdx.x * 256 + threadIdx.x;
    const int total = S * NJ * HD;
    if (idx >= total) return;
    int t = idx / FUSED_N;
    int rem = idx - t * FUSED_N;
    int j = rem >> 6;
    int d = rem & 63;
    float x = fused[idx];
    if (j == 33) { v[t * HD + d] = x; return; }
    int i = d & 31;
    double inv = exp2(-(double)i * (13.287712379549449 / 32.0)); // 10000^(-i/32)
    double ang = (double)t * inv;
    float c  = (float)cos(ang);
    float sn = (float)sin(ang);
    float xo = fused[idx - d + ((d < 32) ? (d + 32) : (d - 32))];
    float rot = (d < 32) ? -xo : xo;
    unsigned short outv = f2bf(x * c + rot * sn);
    if (j == 32) kb[t * HD + d] = outv;
    else         qb[(size_t)t * HDIM + j * HD + d] = outv;
}

// ---------------------------------------------------------------------------
// z_kernel: Zinv[t][h] = 1 / sum_c exp(q_h[t]·k[c]/8)
// ---------------------------------------------------------------------------
__global__ __launch_bounds__(256) void z_kernel(const unsigned short* __restrict__ qb,
                                                const unsigned short* __restrict__ kb,
                                                float* __restrict__ zinv)
{
    const int t0 = blockIdx.x * 32;
    const int h  = blockIdx.y;
    const int w    = threadIdx.x >> 6;
    const int lane = threadIdx.x & 63;
    const int rsub = lane & 15;
    const int d0   = (lane >> 4) * 8;
    __shared__ float zl[4][32];

    short8 a[2][2];
#pragma unroll
    for (int mt = 0; mt < 2; ++mt) {
        const short8* ap = (const short8*)(qb + (size_t)(t0 + mt * 16 + rsub) * HDIM + h * HD + d0);
        a[mt][0] = ap[0];
        a[mt][1] = ap[4];
    }
    float z[2][4] = {};
    for (int nt = 0; nt < 32; ++nt) {
        const int c = w * 512 + nt * 16 + rsub;
        const short8* bp = (const short8*)(kb + (size_t)c * HD + d0);
        short8 b0 = bp[0];
        short8 b1 = bp[4];
#pragma unroll
        for (int mt = 0; mt < 2; ++mt) {
            floatx4 acc = {0.f, 0.f, 0.f, 0.f};
            acc = __builtin_amdgcn_mfma_f32_16x16x32_bf16(a[mt][0], b0, acc, 0, 0, 0);
            acc = __builtin_amdgcn_mfma_f32_16x16x32_bf16(a[mt][1], b1, acc, 0, 0, 0);
#pragma unroll
            for (int r = 0; r < 4; ++r) z[mt][r] += __expf(acc[r] * 0.125f);
        }
    }
#pragma unroll
    for (int mt = 0; mt < 2; ++mt)
#pragma unroll
        for (int r = 0; r < 4; ++r) {
            float zz = z[mt][r];
#pragma unroll
            for (int off = 1; off < 16; off <<= 1) zz += __shfl_xor(zz, off);
            z[mt][r] = zz;
        }
    if (rsub == 0) {
#pragma unroll
        for (int mt = 0; mt < 2; ++mt)
#pragma unroll
            for (int r = 0; r < 4; ++r)
                zl[w][mt * 16 + (lane >> 4) * 4 + r] = z[mt][r];
    }
    __syncthreads();
    if (threadIdx.x < 32) {
        float s = zl[0][threadIdx.x] + zl[1][threadIdx.x] + zl[2][threadIdx.x] + zl[3][threadIdx.x];
        zinv[(size_t)(t0 + threadIdx.x) * NH + h] = 1.0f / s;
    }
}

// ---------------------------------------------------------------------------
// pnorm_kernel: P[t][c] = sum_h exp(q_h[t]·k[c]/8) * zinv[t][h]
// ---------------------------------------------------------------------------
__global__ __launch_bounds__(256) void pnorm_kernel(const unsigned short* __restrict__ qb,
                                                    const unsigned short* __restrict__ kb,
                                                    const float* __restrict__ zinv,
                                                    float* __restrict__ P)
{
    const int t0 = blockIdx.y * 32;
    const int cb = blockIdx.x * 256;
    const int w    = threadIdx.x >> 6;
    const int lane = threadIdx.x & 63;
    const int rsub = lane & 15;
    const int d0   = (lane >> 4) * 8;
    __shared__ float zi[32][33];
    for (int i = threadIdx.x; i < 32 * 32; i += 256) {
        int row = i >> 5, hh = i & 31;
        zi[row][hh] = zinv[(size_t)(t0 + row) * NH + hh];
    }
    __syncthreads();

    float pacc[2][4][4] = {};
    for (int h = 0; h < NH; ++h) {
        short8 a[2][2];
#pragma unroll
        for (int mt = 0; mt < 2; ++mt) {
            const short8* ap = (const short8*)(qb + (size_t)(t0 + mt * 16 + rsub) * HDIM + h * HD + d0);
            a[mt][0] = ap[0];
            a[mt][1] = ap[4];
        }
        float zv[2][4];
#pragma unroll
        for (int mt = 0; mt < 2; ++mt)
#pragma unroll
            for (int r = 0; r < 4; ++r)
                zv[mt][r] = zi[mt * 16 + (lane >> 4) * 4 + r][h];
#pragma unroll
        for (int nt = 0; nt < 4; ++nt) {
            const int c = cb + w * 64 + nt * 16 + rsub;
            const short8* bp = (const short8*)(kb + (size_t)c * HD + d0);
            short8 b0 = bp[0];
            short8 b1 = bp[4];
#pragma unroll
            for (int mt = 0; mt < 2; ++mt) {
                floatx4 acc = {0.f, 0.f, 0.f, 0.f};
                acc = __builtin_amdgcn_mfma_f32_16x16x32_bf16(a[mt][0], b0, acc, 0, 0, 0);
                acc = __builtin_amdgcn_mfma_f32_16x16x32_bf16(a[mt][1], b1, acc, 0, 0, 0);
#pragma unroll
                for (int r = 0; r < 4; ++r)
                    pacc[mt][nt][r] += __expf(acc[r] * 0.125f) * zv[mt][r];
            }
        }
    }
#pragma unroll
    for (int mt = 0; mt < 2; ++mt)
#pragma unroll
        for (int nt = 0; nt < 4; ++nt)
#pragma unroll
            for (int r = 0; r < 4; ++r) {
                int row = t0 + mt * 16 + (lane >> 4) * 4 + r;
                int col = cb + w * 64 + nt * 16 + rsub;
                P[(size_t)row * S + col] = pacc[mt][nt][r];
            }
}

// ---------------------------------------------------------------------------
// acc_init: acc[c] = (c<256 ? sum_{t<256} P[t][c] : 0) + (c<=256 ? P[256][c] : 0)
// ---------------------------------------------------------------------------
__global__ __launch_bounds__(256) void acc_init_kernel(const float* __restrict__ P,
                                                       float* __restrict__ acc_init)
{
    int c = blockIdx.x * 256 + threadIdx.x;
    float s = 0.f;
    if (c < 256) {
        const float* p = P + c;
        float s0 = 0.f, s1 = 0.f, s2 = 0.f, s3 = 0.f;
#pragma unroll 4
        for (int t = 0; t < 256; t += 4) {
            s0 += p[(size_t)t * S];
            s1 += p[(size_t)(t + 1) * S];
            s2 += p[(size_t)(t + 2) * S];
            s3 += p[(size_t)(t + 3) * S];
        }
        s = (s0 + s1) + (s2 + s3);
    }
    if (c <= 256) s += P[(size_t)256 * S + c];
    acc_init[c] = s;
}

// ---------------------------------------------------------------------------
// nv_kernel: NV[c] = candidate value of column c when it becomes newc at step
// t = c+129 (bit-exact vs the sequential accumulation; see round-7 notes).
// Also zeroes the scan-done flag each launch (graph-replay deterministic).
// ---------------------------------------------------------------------------
__global__ __launch_bounds__(256) void nv_kernel(const float* __restrict__ P,
                                                 const float* __restrict__ acc_init,
                                                 float* __restrict__ NV,
                                                 int* __restrict__ done)
{
    if (blockIdx.x == 0 && threadIdx.x == 0) *done = 0;
    int c = 128 + blockIdx.x * 256 + threadIdx.x;
    if (c > 1918) return;
    float s;
    int t0;
    if (c <= 256) { s = acc_init[c]; t0 = 257; }
    else          { s = P[(size_t)c * S + c]; t0 = c + 1; }
    const int t1 = c + 128;
    const float* p = P + c;
    for (int t = t0; t <= t1; ++t)
        s += p[(size_t)t * S];
    NV[c] = s;
}

// ---------------------------------------------------------------------------
// Sequential heavy-hitter scan — scan wave byte-identical to r13 (verified).
// BURNER A/B (r14): high-duty ILP-4 FMA with ~16x longer poll period.
//   r13: serial FMA (12% VALUBusy, weak DPM signal), poll every ~1.7us.
//   r12 failure isolated to poll-storm (4096 waves, continuous agent-scope
//   polls of one line) + 4x waves — NOT burn duty per se.
//   r14: 256 blocks (1/CU), ILP-4 FMA (~full SIMD issue -> strong DPM
//   signal), poll every ~15-25us (10x less poll traffic than r13).
//   Tail cost bounded by poll period (~25us).
// ---------------------------------------------------------------------------
#define GLOAD(dst, ptr) asm volatile("global_load_dword %0, %1, off" : "=v"(dst) : "v"(ptr))
#define GLOAD_S(dst, voff, base) asm volatile("global_load_dword %0, %1, %2" : "=v"(dst) : "v"(voff), "s"(base))
#define GSTORE_S(voff, val, base) asm volatile("global_store_short %0, %1, %2" :: "v"(voff), "v"(val), "s"(base) : "memory")

// one scan step consuming bank (A0x,A1x,AYx,SNx,NVx), then reloading it for t+2
#define SCAN_STEP(t, A0x, A1x, AYx, SNx, NVx)                                        \
    {                                                                                \
        unsigned p0 = (__float_as_uint(v0) & 0xFFFFF800u) | (unsigned)ic0;           \
        unsigned p1 = (__float_as_uint(v1) & 0xFFFFF800u) | (unsigned)ic1;           \
        unsigned xv = p0 < p1 ? p0 : p1;                                             \
        asm("v_min_u32 %0, %0, %0 row_shr:1 row_mask:0xf bank_mask:0xf" : "+v"(xv)); \
        asm("v_min_u32 %0, %0, %0 row_shr:2 row_mask:0xf bank_mask:0xf" : "+v"(xv)); \
        asm("v_min_u32 %0, %0, %0 row_shr:4 row_mask:0xf bank_mask:0xf" : "+v"(xv)); \
        asm("v_min_u32 %0, %0, %0 row_shr:8 row_mask:0xf bank_mask:0xf" : "+v"(xv)); \
        asm("v_min_u32 %0, %0, %0 row_bcast:15 row_mask:0xa bank_mask:0xf" : "+v"(xv));\
        asm("v_min_u32 %0, %0, %0 row_bcast:31 row_mask:0xc bank_mask:0xf" : "+v"(xv));\
        unsigned mpk = (unsigned)__builtin_amdgcn_readlane((int)xv, 63);             \
        asm volatile("s_waitcnt vmcnt(7)" ::: "memory");                             \
        __builtin_amdgcn_sched_barrier(0);                                           \
        const int newc = (t) - 129;                                                  \
        unsigned pn = (__float_as_uint(NVx) & 0xFFFFF800u) | (unsigned)(2047 - newc);\
        const bool evict = mpk < pn;        /* masked strict-<; ties keep heavy */   \
        float pv0 = e0p ? AYx : A0x;                                                 \
        float pv1 = e1p ? AYx : A1x;                                                 \
        const int mcic = (int)(mpk & 2047u);                                         \
        bool e0 = evict && (ic0 == mcic);                                            \
        bool e1 = evict && (ic1 == mcic);                                            \
        v0 = e0 ? (NVx + SNx) : (v0 + pv0);                                          \
        c0 = e0 ? newc : c0;                                                         \
        ic0 = e0 ? (2047 - newc) : ic0;                                              \
        v1 = e1 ? (NVx + SNx) : (v1 + pv1);                                          \
        c1 = e1 ? newc : c1;                                                         \
        ic1 = e1 ? (2047 - newc) : ic1;                                              \
        {                                                                            \
            const unsigned short* hb = heavy + (size_t)(t) * HEAVY_K;                \
            GSTORE_S(vlane0, (unsigned)(unsigned short)c0, hb);                      \
            GSTORE_S(vlane1, (unsigned)(unsigned short)c1, hb);                      \
        }                                                                            \
        e0p = e0; e1p = e1;                                                          \
        {                                                                            \
            const int t2 = ((t) + 2 < S) ? ((t) + 2) : (S - 1);                      \
            const float* P2 = P + (size_t)t2 * S;                                    \
            unsigned vo0 = (unsigned)c0 << 2, vo1 = (unsigned)c1 << 2;               \
            GLOAD_S(A0x, vo0, P2);                                                   \
            GLOAD_S(A1x, vo1, P2);                                                   \
            GLOAD_S(AYx, vzero, P2 + ((t) - 128));     /* P[t+2][newc(t+1)] */       \
            GLOAD_S(SNx, vzero, P2 + (t2 - 129));      /* pnew(t+2)         */       \
            GLOAD_S(NVx, vzero, NV + (t2 - 129));                                    \
        }                                                                            \
    }

__global__ __launch_bounds__(256) void scan_kernel(const float* __restrict__ P,
                                                   const float* __restrict__ acc_init,
                                                   const float* __restrict__ NV,
                                                   unsigned short* __restrict__ heavy,
                                                   int* __restrict__ done)
{
    if (blockIdx.x != 0 || threadIdx.x >= 64) {
        // ---- burner: ILP-4 FMA (high VALU duty), infrequent agent polls ----
        float a = 1.0f + (float)(threadIdx.x & 63);
        float b = 1.000001f;
        float q0 = 0.f, q1 = 1.f, q2 = 2.f, q3 = 3.f;
        while (__hip_atomic_load(done, __ATOMIC_ACQUIRE, __HIP_MEMORY_SCOPE_AGENT) == 0) {
#pragma unroll 16
            for (int i = 0; i < 4096; ++i) {
                q0 = fmaf(a, b, q0); q1 = fmaf(a, b, q1);
                q2 = fmaf(a, b, q2); q3 = fmaf(a, b, q3);
            }
            asm volatile("" :: "v"(q0), "v"(q1), "v"(q2), "v"(q3));
        }
        return;
    }

    const int lane = threadIdx.x;           // wave 0 of block 0: the serial scan

    heavy[START_T * HEAVY_K + lane] = (unsigned short)lane;
    heavy[START_T * HEAVY_K + 64 + lane] = (unsigned short)(lane + 64);

    int   c0 = lane, c1 = lane + 64;
    int   ic0 = 2047 - c0, ic1 = 2047 - c1;
    float v0 = acc_init[lane], v1 = acc_init[lane + 64];
    const unsigned vlane0 = (unsigned)lane * 2;        // byte offsets into heavy row
    const unsigned vlane1 = (unsigned)lane * 2 + 128;
    unsigned vzero = 0;
    asm volatile("" : "+v"(vzero));                     // pin 0 in a VGPR

    // ---- prologue: bank0 = group(257), bank1 = group(258); drain ----
    float A0a, A1a, AYa, SNa, NVa;   // bank0
    float A0b, A1b, AYb, SNb, NVb;   // bank1
    {
        const float* Pa = P + (size_t)257 * S;
        GLOAD(A0a, Pa + c0);
        GLOAD(A1a, Pa + c1);
        GLOAD(AYa, Pa);               // dummy (e0p false at t=257)
        GLOAD(SNa, Pa + 128);         // pnew(257), newc=128
        GLOAD(NVa, NV + 128);
        const float* Pb = P + (size_t)258 * S;
        GLOAD(A0b, Pb + c0);
        GLOAD(A1b, Pb + c1);
        GLOAD(AYb, Pb + 128);         // P[258][newc(257)]
        GLOAD(SNb, Pb + 129);
        GLOAD(NVb, NV + 129);
    }
    asm volatile("s_waitcnt vmcnt(0)" ::: "memory");
    __builtin_amdgcn_sched_barrier(0);

    bool e0p = false, e1p = false;

    int t = START_T + 1;                       // 257
    for (; t + 1 < S; t += 2) {
        SCAN_STEP(t,     A0a, A1a, AYa, SNa, NVa);
        SCAN_STEP(t + 1, A0b, A1b, AYb, SNb, NVb);
    }
    SCAN_STEP(t, A0a, A1a, AYa, SNa, NVa);     // t = 2047

    if (lane == 0) {
        __threadfence();
        __hip_atomic_store(done, 1, __ATOMIC_RELEASE, __HIP_MEMORY_SCOPE_AGENT);
    }
}

// ---------------------------------------------------------------------------
// Sparse masked attention: row t attends to {128 heavy} ∪ [t-128, t]
// ---------------------------------------------------------------------------
__global__ __launch_bounds__(256) void attn_kernel(const unsigned short* __restrict__ qb,
                                                   const unsigned short* __restrict__ kb,
                                                   const float* __restrict__ v,
                                                   const unsigned short* __restrict__ heavy,
                                                   float* __restrict__ attn)
{
    const int t = blockIdx.x;
    const int tid = threadIdx.x;
    __shared__ float qs[HDIM];
    __shared__ float sc[NH][258];
    __shared__ unsigned short cols[260];
    __shared__ float zpart[NH][8];
    __shared__ float zf[NH];
    const int cnt = (t < START_T) ? (t + 1) : 257;
    {
        const short8* qr = (const short8*)(qb + (size_t)t * HDIM);
        short8 qv = qr[tid];
#pragma unroll
        for (int j = 0; j < 8; ++j) qs[tid * 8 + j] = bf2f((unsigned short)qv[j]);
    }
    if (t < START_T) {
        for (int j = tid; j < cnt; j += 256) cols[j] = (unsigned short)j;
    } else {
        if (tid < 128) cols[tid] = heavy[(size_t)t * HEAVY_K + tid];
        else           cols[tid] = (unsigned short)(t - 256 + tid);
        if (tid == 0)  cols[256] = (unsigned short)t;
    }
    __syncthreads();
    {
        const int h = tid & 31;
        const float* qh = qs + h * HD;
        for (int j = tid >> 5; j < cnt; j += 8) {
            const short8* kc8 = (const short8*)(kb + (size_t)cols[j] * HD);
            float s = 0.f;
#pragma unroll
            for (int dq = 0; dq < 8; ++dq) {
                short8 kv = kc8[dq];
#pragma unroll
                for (int e = 0; e < 8; ++e)
                    s += qh[dq * 8 + e] * bf2f((unsigned short)kv[e]);
            }
            sc[h][j] = s * 0.125f;
        }
    }
    __syncthreads();
    {
        const int h2 = tid >> 3, sub = tid & 7;
        float z = 0.f;
        for (int j = sub; j < cnt; j += 8) {
            float e = __expf(sc[h2][j]);
            sc[h2][j] = e;
            z += e;
        }
        zpart[h2][sub] = z;
    }
    __syncthreads();
    if (tid < NH) {
        float z = 0.f;
#pragma unroll
        for (int s2 = 0; s2 < 8; ++s2) z += zpart[tid][s2];
        zf[tid] = 1.0f / z;
    }
    __syncthreads();
    {
        const int h2 = tid >> 3;
        const int dbase = (tid & 7) * 8;
        float o[8] = {0, 0, 0, 0, 0, 0, 0, 0};
        for (int j = 0; j < cnt; ++j) {
            float p = sc[h2][j];
            const float* vc = v + (size_t)cols[j] * HD + dbase;
            float4 va = *(const float4*)vc;
            float4 vb = *(const float4*)(vc + 4);
            o[0] += p * va.x; o[1] += p * va.y; o[2] += p * va.z; o[3] += p * va.w;
            o[4] += p * vb.x; o[5] += p * vb.y; o[6] += p * vb.z; o[7] += p * vb.w;
        }
        float zi = zf[h2];
        float* op = attn + (size_t)t * HDIM + h2 * HD + dbase;
        float4 ra = make_float4(o[0] * zi, o[1] * zi, o[2] * zi, o[3] * zi);
        float4 rb = make_float4(o[4] * zi, o[5] * zi, o[6] * zi, o[7] * zi);
        *(float4*)op = ra;
        *(float4*)(op + 4) = rb;
    }
}

// ---------------------------------------------------------------------------
extern "C" void kernel_launch(void* const* d_in, const int* in_sizes, int n_in,
                              void* d_out, int out_size, void* d_ws, size_t ws_size,
                              hipStream_t stream)
{
    (void)in_sizes; (void)n_in; (void)out_size; (void)ws_size;
    const float* hs      = (const float*)d_in[0];
    const float* w_qkv   = (const float*)d_in[1];
    const float* w_dense = (const float*)d_in[2];
    float* out = (float*)d_out;
    char* ws = (char*)d_ws;

    // workspace layout (bytes):
    //   [0, 17825792)            fused (2048x2176 f32) -> P (2048x2048 f32) -> attn (2048x2048 f32)
    //   [17825792, 26214400)     qb  bf16 [2048][2048]
    //   [26214400, 26476544)     kb  bf16 [2048][64]
    //   [26476544, 27000832)     v   f32  [2048][64]
    //   [27000832, 27262976)     zinv f32 [2048][32]
    //   [27262976, 27787264)     heavy ushort [2048][128]
    //   [27787264, 27795456)     acc_init f32 [2048]
    //   [27795456, 27803648)     NV f32 [2048]
    //   [27803648, 27803652)     done flag (int)
    float* fused = (float*)(ws);
    float* P     = (float*)(ws);
    float* attn  = (float*)(ws);
    unsigned short* qb = (unsigned short*)(ws + 17825792);
    unsigned short* kb = (unsigned short*)(ws + 26214400);
    float* v           = (float*)(ws + 26476544);
    float* zinv        = (float*)(ws + 27000832);
    unsigned short* heavy = (unsigned short*)(ws + 27262976);
    float* acc_init       = (float*)(ws + 27787264);
    float* NV             = (float*)(ws + 27795456);
    int* done             = (int*)(ws + 27803648);

    dim3 g1(FUSED_N / GBN, S / GBM);     // (17, 16)
    gemm_nt_mfma<<<g1, 256, 0, stream>>>(hs, w_qkv, fused, S, FUSED_N, HDIM);

    int total = S * NJ * HD;
    rope_split_kernel<<<(total + 255) / 256, 256, 0, stream>>>(fused, qb, kb, v);

    dim3 gz(S / 32, NH);
    z_kernel<<<gz, 256, 0, stream>>>(qb, kb, zinv);

    dim3 gp(S / 256, S / 32);
    pnorm_kernel<<<gp, 256, 0, stream>>>(qb, kb, zinv, P);

    acc_init_kernel<<<S / 256, 256, 0, stream>>>(P, acc_init);

    nv_kernel<<<7, 256, 0, stream>>>(P, acc_init, NV, done);

    scan_kernel<<<256, 256, 0, stream>>>(P, acc_init, NV, heavy, done);

    attn_kernel<<<S, 256, 0, stream>>>(qb, kb, v, heavy, attn);

    dim3 g2(HDIM / GBN, S / GBM);        // (16, 16)
    gemm_nt_mfma<<<g2, 256, 0, stream>>>(attn, w_dense, out, S, HDIM, HDIM);
}